// Round 1
// baseline (4148.404 us; speedup 1.0000x reference)
//
#include <hip/hip_runtime.h>
#include <math.h>

#define HH 192
#define WW 192
#define HWSZ (HH*WW)
#define BB 4

// ---------------- generic 3x3 conv, pad=1, fp32 direct ----------------
// block = 16x16 pixels, each thread computes OCB=16 output channels for its pixel.
// input tile staged in LDS 4 cin at a time; weights read at uniform addresses
// (compiler emits s_load -> SMEM pipe, VALU stays on FMAs).
template<int CIN, bool RELU>
__global__ __launch_bounds__(256) void conv3x3_kernel(
    const float* __restrict__ in, const float* __restrict__ w,
    const float* __restrict__ bias, float* __restrict__ out,
    int nOcTiles, int coutTot, int ocOff)
{
    constexpr int OCB = 16;
    constexpr int CCH = 4;
    __shared__ float s_in[CCH][18][18];

    const int tx = threadIdx.x, ty = threadIdx.y;
    const int tid = ty * 16 + tx;
    const int bx = blockIdx.x * 16, by = blockIdx.y * 16;
    const int b   = blockIdx.z / nOcTiles;
    const int oc0 = (blockIdx.z % nOcTiles) * OCB;
    const int ox = bx + tx, oy = by + ty;

    float acc[OCB];
#pragma unroll
    for (int o = 0; o < OCB; ++o) acc[o] = 0.f;

    for (int c0 = 0; c0 < CIN; c0 += CCH) {
        // stage 4 input channels of an 18x18 halo tile
        for (int i = tid; i < CCH * 324; i += 256) {
            int c = i / 324, rem = i % 324;
            int r = rem / 18, col = rem % 18;
            int gy = by + r - 1, gx = bx + col - 1;
            float v = 0.f;
            if (gy >= 0 && gy < HH && gx >= 0 && gx < WW)
                v = in[((size_t)(b * CIN + c0 + c) * HH + gy) * WW + gx];
            s_in[c][r][col] = v;
        }
        __syncthreads();
#pragma unroll
        for (int c = 0; c < CCH; ++c) {
            float v[9];
#pragma unroll
            for (int t = 0; t < 9; ++t)
                v[t] = s_in[c][ty + t / 3][tx + t % 3];
            const float* wp = w + ((size_t)oc0 * CIN + (c0 + c)) * 9;
#pragma unroll
            for (int o = 0; o < OCB; ++o) {
#pragma unroll
                for (int t = 0; t < 9; ++t)
                    acc[o] = fmaf(v[t], wp[(size_t)o * CIN * 9 + t], acc[o]);
            }
        }
        __syncthreads();
    }
#pragma unroll
    for (int o = 0; o < OCB; ++o) {
        float r = acc[o] + bias[oc0 + o];
        if (RELU) r = fmaxf(r, 0.f);
        out[((size_t)(b * coutTot + ocOff + oc0 + o) * HH + oy) * WW + ox] = r;
    }
}

// ---------------- dcn weight transpose: (o,c,k) -> (c*9+k, o) ----------------
__global__ void transpose_w_kernel(const float* __restrict__ w, float* __restrict__ wT)
{
    int i = blockIdx.x * 256 + threadIdx.x;
    if (i < 64 * 64 * 9) {
        int o = i / 576, rem = i % 576;
        int c = rem / 9, k = rem % 9;
        wT[(c * 9 + k) * 64 + o] = w[i];
    }
}

// ---------------- deformable conv (groups=8, K=9, C=64) + relu ----------------
// thread per pixel; acc[64]; weights read contiguous+uniform from wT.
__global__ __launch_bounds__(256) void deform_kernel(
    const float* __restrict__ x, const float* __restrict__ off,
    const float* __restrict__ wT, const float* __restrict__ bias,
    float* __restrict__ cat)
{
    const int tx = threadIdx.x, ty = threadIdx.y;
    const int px_ = blockIdx.x * 16 + tx;
    const int py_ = blockIdx.y * 16 + ty;
    const int b = blockIdx.z;

    float acc[64];
#pragma unroll
    for (int o = 0; o < 64; ++o) acc[o] = 0.f;

    for (int g = 0; g < 8; ++g) {
        const float* xg = x + (size_t)(b * 64 + g * 8) * HWSZ;
        for (int k = 0; k < 9; ++k) {
            int kyy = k / 3, kxx = k % 3;
            size_t oidx = ((size_t)(b * 144 + g * 18 + k * 2) * HH + py_) * WW + px_;
            float dy = off[oidx];
            float dx = off[oidx + HWSZ];
            float pyf = (float)(py_ + kyy - 1) + dy;
            float pxf = (float)(px_ + kxx - 1) + dx;
            float fy = floorf(pyf), fx = floorf(pxf);
            float wy = pyf - fy, wx = pxf - fx;
            int iy = (int)fy, ix = (int)fx;
            float w00 = (1.f - wy) * (1.f - wx), w01 = (1.f - wy) * wx;
            float w10 = wy * (1.f - wx),         w11 = wy * wx;
            bool y0v = (iy >= 0) && (iy < HH);
            bool y1v = (iy + 1 >= 0) && (iy + 1 < HH);
            bool x0v = (ix >= 0) && (ix < WW);
            bool x1v = (ix + 1 >= 0) && (ix + 1 < WW);
            if (!(y0v && x0v)) w00 = 0.f;
            if (!(y0v && x1v)) w01 = 0.f;
            if (!(y1v && x0v)) w10 = 0.f;
            if (!(y1v && x1v)) w11 = 0.f;
            int cy0 = min(max(iy, 0), HH - 1),     cy1 = min(max(iy + 1, 0), HH - 1);
            int cx0 = min(max(ix, 0), WW - 1),     cx1 = min(max(ix + 1, 0), WW - 1);
            int i00 = cy0 * WW + cx0, i01 = cy0 * WW + cx1;
            int i10 = cy1 * WW + cx0, i11 = cy1 * WW + cx1;
#pragma unroll
            for (int cc = 0; cc < 8; ++cc) {
                const float* xp = xg + (size_t)cc * HWSZ;
                float v = xp[i00] * w00 + xp[i01] * w01 + xp[i10] * w10 + xp[i11] * w11;
                const float* wrow = wT + (size_t)((g * 8 + cc) * 9 + k) * 64;
#pragma unroll
                for (int o = 0; o < 64; ++o)
                    acc[o] = fmaf(v, wrow[o], acc[o]);
            }
        }
    }
#pragma unroll
    for (int o = 0; o < 64; ++o) {
        float r = fmaxf(acc[o] + bias[o], 0.f);
        cat[((size_t)(b * 128 + o) * HH + py_) * WW + px_] = r;
    }
}

// ---------------- global average pool: one block per (b,c) ----------------
__global__ __launch_bounds__(256) void pool_kernel(const float* __restrict__ x, float* __restrict__ gout)
{
    int bc = blockIdx.x;
    const float* p = x + (size_t)bc * HWSZ;
    int tid = threadIdx.x;
    float s = 0.f;
    for (int i = tid * 4; i < HWSZ; i += 256 * 4) {
        float4 v = *reinterpret_cast<const float4*>(p + i);
        s += v.x + v.y + v.z + v.w;
    }
#pragma unroll
    for (int o = 32; o > 0; o >>= 1) s += __shfl_down(s, o, 64);
    __shared__ float red[4];
    if ((tid & 63) == 0) red[tid >> 6] = s;
    __syncthreads();
    if (tid == 0) gout[bc] = (red[0] + red[1] + red[2] + red[3]) * (1.f / (float)HWSZ);
}

// ---------------- SE MLP: sigmoid(relu(g@w1^T+b1)@w2^T+b2) ----------------
__global__ __launch_bounds__(256) void se_kernel(
    const float* __restrict__ g, const float* __restrict__ w1, const float* __restrict__ b1,
    const float* __restrict__ w2, const float* __restrict__ b2, float* __restrict__ a)
{
    __shared__ float sg[BB * 64];
    __shared__ float sh[BB * 32];
    int tid = threadIdx.x;
    sg[tid] = g[tid];                 // 256 == BB*64
    __syncthreads();
    if (tid < BB * 32) {
        int b = tid / 32, h = tid % 32;
        float s = b1[h];
        for (int c = 0; c < 64; ++c) s += sg[b * 64 + c] * w1[h * 64 + c];
        sh[b * 32 + h] = fmaxf(s, 0.f);
    }
    __syncthreads();
    {
        int b = tid / 64, o = tid % 64;
        float s = b2[o];
        for (int h = 0; h < 32; ++h) s += sh[b * 32 + h] * w2[o * 32 + h];
        a[tid] = 1.f / (1.f + expf(-s));
    }
}

// ---------------- residual + SE scale, in place on d_out ----------------
__global__ __launch_bounds__(256) void final_kernel(
    float* __restrict__ out, const float* __restrict__ cat, const float* __restrict__ a)
{
    const int VPC = HWSZ / 4;  // 9216 float4 per channel
    int v = blockIdx.x * 256 + threadIdx.x;   // 0 .. BB*64*VPC-1
    int bc = v / VPC, within = v % VPC;
    int b = bc >> 6, c = bc & 63;
    float av = a[bc];
    float4 xo = reinterpret_cast<float4*>(out)[v];
    float4 df = reinterpret_cast<const float4*>(cat)[(size_t)(b * 128 + c) * VPC + within];
    float4 r;
    r.x = df.x + xo.x * av;
    r.y = df.y + xo.y * av;
    r.z = df.z + xo.z * av;
    r.w = df.w + xo.w * av;
    reinterpret_cast<float4*>(out)[v] = r;
}

extern "C" void kernel_launch(void* const* d_in, const int* in_sizes, int n_in,
                              void* d_out, int out_size, void* d_ws, size_t ws_size,
                              hipStream_t stream) {
    const float* mv     = (const float*)d_in[0];
    const float* ref    = (const float*)d_in[1];
    const float* head_w = (const float*)d_in[2];
    const float* head_b = (const float*)d_in[3];
    const float* dcn_w  = (const float*)d_in[4];
    const float* dcn_b  = (const float*)d_in[5];
    const float* c1w1   = (const float*)d_in[6];
    const float* c1b1   = (const float*)d_in[7];
    const float* c1w2   = (const float*)d_in[8];
    const float* c1b2   = (const float*)d_in[9];
    const float* aux_w  = (const float*)d_in[10];
    const float* aux_b  = (const float*)d_in[11];
    const float* fw1    = (const float*)d_in[12];
    const float* fb1    = (const float*)d_in[13];
    const float* fw2    = (const float*)d_in[14];
    const float* fb2    = (const float*)d_in[15];
    const float* se_w1  = (const float*)d_in[16];
    const float* se_b1  = (const float*)d_in[17];
    const float* se_w2  = (const float*)d_in[18];
    const float* se_b2  = (const float*)d_in[19];
    float* out = (float*)d_out;

    float* ws = (float*)d_ws;
    const size_t SZ_OFF = (size_t)BB * 144 * HWSZ;   // 21,233,664
    const size_t SZ_128 = (size_t)BB * 128 * HWSZ;   // 18,874,368
    float* off_buf = ws;                 // region 1 (also reused for t1)
    float* t1      = ws;
    float* r2      = ws + SZ_OFF;        // region 2: aux_in, later x1
    float* cat     = r2 + SZ_128;        // region 3: [def(0:64) | aux(64:128)]
    float* wT      = cat + SZ_128;
    float* gbuf    = wT + 64 * 64 * 9;
    float* abuf    = gbuf + 256;

    dim3 blk(16, 16);

    // 0. dcn weight transpose
    transpose_w_kernel<<<144, 256, 0, stream>>>(dcn_w, wT);
    // 1. offsets = conv(mv, head_w)            128 -> 144
    conv3x3_kernel<128, false><<<dim3(12, 12, BB * 9), blk, 0, stream>>>(
        mv, head_w, head_b, off_buf, 9, 144, 0);
    // 2. def_feat = relu(deform(ref, offsets)) -> cat[:, 0:64]
    deform_kernel<<<dim3(12, 12, BB), blk, 0, stream>>>(ref, off_buf, wT, dcn_b, cat);
    // 3. t1 = relu(conv(ref, c1w1))            64 -> 128   (overwrites off region)
    conv3x3_kernel<64, true><<<dim3(12, 12, BB * 8), blk, 0, stream>>>(
        ref, c1w1, c1b1, t1, 8, 128, 0);
    // 4. aux_in = relu(conv(t1, c1w2))         128 -> 128
    conv3x3_kernel<128, true><<<dim3(12, 12, BB * 8), blk, 0, stream>>>(
        t1, c1w2, c1b2, r2, 8, 128, 0);
    // 5. aux = relu(conv(aux_in, aux_w))       128 -> 64   -> cat[:, 64:128]
    conv3x3_kernel<128, true><<<dim3(12, 12, BB * 4), blk, 0, stream>>>(
        r2, aux_w, aux_b, cat, 4, 128, 64);
    // 6. x1 = relu(conv(cat, fw1))             128 -> 64   (reuses r2)
    conv3x3_kernel<128, true><<<dim3(12, 12, BB * 4), blk, 0, stream>>>(
        cat, fw1, fb1, r2, 4, 64, 0);
    // 7. x2 = conv(x1, fw2)                    64 -> 64    -> d_out
    conv3x3_kernel<64, false><<<dim3(12, 12, BB * 4), blk, 0, stream>>>(
        r2, fw2, fb2, out, 4, 64, 0);
    // 8. g = mean(x2)
    pool_kernel<<<BB * 64, 256, 0, stream>>>(out, gbuf);
    // 9. a = sigmoid(relu(g@w1^T+b1)@w2^T+b2)
    se_kernel<<<1, 256, 0, stream>>>(gbuf, se_w1, se_b1, se_w2, se_b2, abuf);
    // 10. out = def_feat + x2 * a   (in place)
    final_kernel<<<(BB * 64 * HWSZ / 4) / 256, 256, 0, stream>>>(out, cat, abuf);
}

// Round 2
// 1332.569 us; speedup vs baseline: 3.1131x; 3.1131x over previous
//
#include <hip/hip_runtime.h>
#include <math.h>

#define HH 192
#define WW 192
#define HWSZ (HH*WW)
#define BB 4

typedef __attribute__((ext_vector_type(8))) short bf16x8;
typedef __attribute__((ext_vector_type(4))) float f32x4;

__device__ __forceinline__ unsigned short f2bf(float f) {
    unsigned int u = __float_as_uint(f);
    u = (u + 0x7FFFu + ((u >> 16) & 1u)) >> 16;
    return (unsigned short)u;
}

// ---------- weight pack: OIHW fp32 -> [tap][cin/32][cout][32] bf16 ----------
__global__ void wprep_kernel(const float* __restrict__ w, unsigned short* __restrict__ wb,
                             int cout, int cin)
{
    int idx = blockIdx.x * 256 + threadIdx.x;
    int n = cout * cin * 9;
    if (idx >= n) return;
    int o = idx / (cin * 9);
    int rem = idx - o * cin * 9;
    int c = rem / 9;
    int t = rem - c * 9;
    int nch = cin >> 5;
    wb[((t * nch + (c >> 5)) * cout + o) * 32 + (c & 31)] = f2bf(w[idx]);
}

// ---------- 3x3 conv, pad=1: bf16 MFMA implicit GEMM ----------
// block: 2 rows x 64 px, all COUT. 4 waves; wave w: row (w&1), px strips (w>>1)*32, +16.
// LDS: X tile [4 rows][72 px][32 cin] bf16, cin-contiguous, 16B-granule XOR swizzle.
template<int CIN, int COUT, bool RELU>
__global__ __launch_bounds__(256) void conv3x3_mfma(
    const float* __restrict__ in, const unsigned short* __restrict__ wb,
    const float* __restrict__ bias, float* __restrict__ out,
    int coutTot, int ocOff)
{
    constexpr int NCH = CIN / 32;
    constexpr int NOC = COUT / 16;
    __shared__ __align__(16) unsigned short sx[4 * 72 * 32];

    const int tid = threadIdx.x;
    const int b  = blockIdx.z;
    const int y0 = blockIdx.y * 2;
    const int x0 = blockIdx.x * 64;
    const int wv = tid >> 6, lane = tid & 63;
    const int l15 = lane & 15, kg = lane >> 4;
    const int rowl = wv & 1, sbase = (wv >> 1) * 32;

    f32x4 acc[NOC][2];
#pragma unroll
    for (int oc = 0; oc < NOC; ++oc) {
        acc[oc][0] = (f32x4){0.f, 0.f, 0.f, 0.f};
        acc[oc][1] = (f32x4){0.f, 0.f, 0.f, 0.f};
    }

    for (int ch = 0; ch < NCH; ++ch) {
        const int c0 = ch * 32;
        // ---- stage: 4 rows x 72 px x 32 cin, global float4 (px-fast, coalesced) ----
#pragma unroll
        for (int it = 0; it < 9; ++it) {
            int i = tid + it * 256;            // 0..2303
            int slot = i % 18;                 // px quad
            int rc = i / 18;                   // r*32 + cin
            int cin = rc & 31, r = rc >> 5;
            int yin = y0 - 1 + r;
            int gx = x0 - 4 + slot * 4;
            float4 v = {0.f, 0.f, 0.f, 0.f};
            if (yin >= 0 && yin < HH && gx >= 0 && gx <= WW - 4)
                v = *(const float4*)(in + ((size_t)(b * CIN + c0 + cin) * HH + yin) * WW + gx);
#pragma unroll
            for (int j = 0; j < 4; ++j) {
                int px = slot * 4 + j;
                int g = ((cin >> 3) ^ ((px >> 1) & 3));
                int off = (r * 72 + px) * 32 + (g << 3) + (cin & 7);
                float fv = (j == 0) ? v.x : (j == 1) ? v.y : (j == 2) ? v.z : v.w;
                sx[off] = f2bf(fv);
            }
        }
        __syncthreads();
        // ---- compute: 9 taps x NOC MFMAs x 2 strips ----
#pragma unroll
        for (int ky = 0; ky < 3; ++ky) {
#pragma unroll
            for (int kx = 0; kx < 3; ++kx) {
                const int r = rowl + ky;
                const int p0 = sbase + l15 + kx + 3;
                const int p1 = p0 + 16;
                bf16x8 b0 = *(const bf16x8*)&sx[(r * 72 + p0) * 32 + ((kg ^ ((p0 >> 1) & 3)) << 3)];
                bf16x8 b1 = *(const bf16x8*)&sx[(r * 72 + p1) * 32 + ((kg ^ ((p1 >> 1) & 3)) << 3)];
                const unsigned short* wp = wb
                    + ((size_t)(((ky * 3 + kx) * NCH + ch) * COUT) + l15) * 32 + kg * 8;
#pragma unroll
                for (int oc = 0; oc < NOC; ++oc) {
                    bf16x8 a = *(const bf16x8*)(wp + oc * 16 * 32);
                    acc[oc][0] = __builtin_amdgcn_mfma_f32_16x16x32_bf16(a, b0, acc[oc][0], 0, 0, 0);
                    acc[oc][1] = __builtin_amdgcn_mfma_f32_16x16x32_bf16(a, b1, acc[oc][1], 0, 0, 0);
                }
            }
        }
        __syncthreads();
    }
    // ---- epilogue: D row = kg*4+j (cout), col = l15 (px) ----
    const int y = y0 + rowl;
    float* obase = out + (size_t)(b * coutTot + ocOff) * HWSZ + y * WW + x0;
#pragma unroll
    for (int oc = 0; oc < NOC; ++oc) {
#pragma unroll
        for (int st = 0; st < 2; ++st) {
            int xo = sbase + st * 16 + l15;
#pragma unroll
            for (int j = 0; j < 4; ++j) {
                int cout = oc * 16 + kg * 4 + j;
                float rv = acc[oc][st][j] + bias[cout];
                if (RELU) rv = fmaxf(rv, 0.f);
                obase[(size_t)cout * HWSZ + xo] = rv;
            }
        }
    }
}

// ---------------- dcn weight transpose: (o,c,k) -> (c*9+k, o) ----------------
__global__ void transpose_w_kernel(const float* __restrict__ w, float* __restrict__ wT)
{
    int i = blockIdx.x * 256 + threadIdx.x;
    if (i < 64 * 64 * 9) {
        int o = i / 576, rem = i % 576;
        int c = rem / 9, k = rem % 9;
        wT[(c * 9 + k) * 64 + o] = w[i];
    }
}

// ---------------- deformable conv (groups=8, K=9, C=64) + relu ----------------
__global__ __launch_bounds__(256) void deform_kernel(
    const float* __restrict__ x, const float* __restrict__ off,
    const float* __restrict__ wT, const float* __restrict__ bias,
    float* __restrict__ cat)
{
    const int tx = threadIdx.x, ty = threadIdx.y;
    const int px_ = blockIdx.x * 16 + tx;
    const int py_ = blockIdx.y * 16 + ty;
    const int b = blockIdx.z;

    float acc[64];
#pragma unroll
    for (int o = 0; o < 64; ++o) acc[o] = 0.f;

    for (int g = 0; g < 8; ++g) {
        const float* xg = x + (size_t)(b * 64 + g * 8) * HWSZ;
        for (int k = 0; k < 9; ++k) {
            int kyy = k / 3, kxx = k % 3;
            size_t oidx = ((size_t)(b * 144 + g * 18 + k * 2) * HH + py_) * WW + px_;
            float dy = off[oidx];
            float dx = off[oidx + HWSZ];
            float pyf = (float)(py_ + kyy - 1) + dy;
            float pxf = (float)(px_ + kxx - 1) + dx;
            float fy = floorf(pyf), fx = floorf(pxf);
            float wy = pyf - fy, wx = pxf - fx;
            int iy = (int)fy, ix = (int)fx;
            float w00 = (1.f - wy) * (1.f - wx), w01 = (1.f - wy) * wx;
            float w10 = wy * (1.f - wx),         w11 = wy * wx;
            bool y0v = (iy >= 0) && (iy < HH);
            bool y1v = (iy + 1 >= 0) && (iy + 1 < HH);
            bool x0v = (ix >= 0) && (ix < WW);
            bool x1v = (ix + 1 >= 0) && (ix + 1 < WW);
            if (!(y0v && x0v)) w00 = 0.f;
            if (!(y0v && x1v)) w01 = 0.f;
            if (!(y1v && x0v)) w10 = 0.f;
            if (!(y1v && x1v)) w11 = 0.f;
            int cy0 = min(max(iy, 0), HH - 1),     cy1 = min(max(iy + 1, 0), HH - 1);
            int cx0 = min(max(ix, 0), WW - 1),     cx1 = min(max(ix + 1, 0), WW - 1);
            int i00 = cy0 * WW + cx0, i01 = cy0 * WW + cx1;
            int i10 = cy1 * WW + cx0, i11 = cy1 * WW + cx1;
#pragma unroll
            for (int cc = 0; cc < 8; ++cc) {
                const float* xp = xg + (size_t)cc * HWSZ;
                float v = xp[i00] * w00 + xp[i01] * w01 + xp[i10] * w10 + xp[i11] * w11;
                const float* wrow = wT + (size_t)((g * 8 + cc) * 9 + k) * 64;
#pragma unroll
                for (int o = 0; o < 64; ++o)
                    acc[o] = fmaf(v, wrow[o], acc[o]);
            }
        }
    }
#pragma unroll
    for (int o = 0; o < 64; ++o) {
        float r = fmaxf(acc[o] + bias[o], 0.f);
        cat[((size_t)(b * 128 + o) * HH + py_) * WW + px_] = r;
    }
}

// ---------------- global average pool ----------------
__global__ __launch_bounds__(256) void pool_kernel(const float* __restrict__ x, float* __restrict__ gout)
{
    int bc = blockIdx.x;
    const float* p = x + (size_t)bc * HWSZ;
    int tid = threadIdx.x;
    float s = 0.f;
    for (int i = tid * 4; i < HWSZ; i += 256 * 4) {
        float4 v = *reinterpret_cast<const float4*>(p + i);
        s += v.x + v.y + v.z + v.w;
    }
#pragma unroll
    for (int o = 32; o > 0; o >>= 1) s += __shfl_down(s, o, 64);
    __shared__ float red[4];
    if ((tid & 63) == 0) red[tid >> 6] = s;
    __syncthreads();
    if (tid == 0) gout[bc] = (red[0] + red[1] + red[2] + red[3]) * (1.f / (float)HWSZ);
}

// ---------------- SE MLP ----------------
__global__ __launch_bounds__(256) void se_kernel(
    const float* __restrict__ g, const float* __restrict__ w1, const float* __restrict__ b1,
    const float* __restrict__ w2, const float* __restrict__ b2, float* __restrict__ a)
{
    __shared__ float sg[BB * 64];
    __shared__ float sh[BB * 32];
    int tid = threadIdx.x;
    sg[tid] = g[tid];
    __syncthreads();
    if (tid < BB * 32) {
        int b = tid / 32, h = tid % 32;
        float s = b1[h];
        for (int c = 0; c < 64; ++c) s += sg[b * 64 + c] * w1[h * 64 + c];
        sh[b * 32 + h] = fmaxf(s, 0.f);
    }
    __syncthreads();
    {
        int b = tid / 64, o = tid % 64;
        float s = b2[o];
        for (int h = 0; h < 32; ++h) s += sh[b * 32 + h] * w2[o * 32 + h];
        a[tid] = 1.f / (1.f + expf(-s));
    }
}

// ---------------- residual + SE scale ----------------
__global__ __launch_bounds__(256) void final_kernel(
    float* __restrict__ out, const float* __restrict__ cat, const float* __restrict__ a)
{
    const int VPC = HWSZ / 4;
    int v = blockIdx.x * 256 + threadIdx.x;
    int bc = v / VPC, within = v % VPC;
    int b = bc >> 6, c = bc & 63;
    float av = a[bc];
    float4 xo = reinterpret_cast<float4*>(out)[v];
    float4 df = reinterpret_cast<const float4*>(cat)[(size_t)(b * 128 + c) * VPC + within];
    float4 r;
    r.x = df.x + xo.x * av;
    r.y = df.y + xo.y * av;
    r.z = df.z + xo.z * av;
    r.w = df.w + xo.w * av;
    reinterpret_cast<float4*>(out)[v] = r;
}

extern "C" void kernel_launch(void* const* d_in, const int* in_sizes, int n_in,
                              void* d_out, int out_size, void* d_ws, size_t ws_size,
                              hipStream_t stream) {
    const float* mv     = (const float*)d_in[0];
    const float* ref    = (const float*)d_in[1];
    const float* head_w = (const float*)d_in[2];
    const float* head_b = (const float*)d_in[3];
    const float* dcn_w  = (const float*)d_in[4];
    const float* dcn_b  = (const float*)d_in[5];
    const float* c1w1   = (const float*)d_in[6];
    const float* c1b1   = (const float*)d_in[7];
    const float* c1w2   = (const float*)d_in[8];
    const float* c1b2   = (const float*)d_in[9];
    const float* aux_w  = (const float*)d_in[10];
    const float* aux_b  = (const float*)d_in[11];
    const float* fw1    = (const float*)d_in[12];
    const float* fb1    = (const float*)d_in[13];
    const float* fw2    = (const float*)d_in[14];
    const float* fb2    = (const float*)d_in[15];
    const float* se_w1  = (const float*)d_in[16];
    const float* se_b1  = (const float*)d_in[17];
    const float* se_w2  = (const float*)d_in[18];
    const float* se_b2  = (const float*)d_in[19];
    float* out = (float*)d_out;

    float* ws = (float*)d_ws;
    const size_t SZ_OFF = (size_t)BB * 144 * HWSZ;
    const size_t SZ_128 = (size_t)BB * 128 * HWSZ;
    float* off_buf = ws;                 // region 1 (reused for t1)
    float* t1      = ws;
    float* r2      = ws + SZ_OFF;        // region 2: aux_in, later x1
    float* cat     = r2 + SZ_128;        // region 3: [def(0:64) | aux(64:128)]
    float* wT      = cat + SZ_128;
    float* gbuf    = wT + 64 * 64 * 9;
    float* abuf    = gbuf + 256;
    unsigned short* wbb = (unsigned short*)(abuf + 256);
    unsigned short* wb_head = wbb;                    // 144*128*9
    unsigned short* wb_c1w1 = wb_head + 165888;       // 128*64*9
    unsigned short* wb_c1w2 = wb_c1w1 + 73728;        // 128*128*9
    unsigned short* wb_aux  = wb_c1w2 + 147456;       // 64*128*9
    unsigned short* wb_fw1  = wb_aux  + 73728;        // 64*128*9
    unsigned short* wb_fw2  = wb_fw1  + 73728;        // 64*64*9

    // weight prep
    transpose_w_kernel<<<144, 256, 0, stream>>>(dcn_w, wT);
    wprep_kernel<<<(144*128*9 + 255)/256, 256, 0, stream>>>(head_w, wb_head, 144, 128);
    wprep_kernel<<<(128*64*9  + 255)/256, 256, 0, stream>>>(c1w1,   wb_c1w1, 128, 64);
    wprep_kernel<<<(128*128*9 + 255)/256, 256, 0, stream>>>(c1w2,   wb_c1w2, 128, 128);
    wprep_kernel<<<(64*128*9  + 255)/256, 256, 0, stream>>>(aux_w,  wb_aux,  64, 128);
    wprep_kernel<<<(64*128*9  + 255)/256, 256, 0, stream>>>(fw1,    wb_fw1,  64, 128);
    wprep_kernel<<<(64*64*9   + 255)/256, 256, 0, stream>>>(fw2,    wb_fw2,  64, 64);

    dim3 cgrid(3, 96, BB);

    // 1. offsets = conv(mv, head_w)            128 -> 144
    conv3x3_mfma<128, 144, false><<<cgrid, 256, 0, stream>>>(mv, wb_head, head_b, off_buf, 144, 0);
    // 2. def_feat = relu(deform(ref, offsets)) -> cat[:, 0:64]
    deform_kernel<<<dim3(12, 12, BB), dim3(16, 16), 0, stream>>>(ref, off_buf, wT, dcn_b, cat);
    // 3. t1 = relu(conv(ref, c1w1))            64 -> 128   (overwrites off region)
    conv3x3_mfma<64, 128, true><<<cgrid, 256, 0, stream>>>(ref, wb_c1w1, c1b1, t1, 128, 0);
    // 4. aux_in = relu(conv(t1, c1w2))         128 -> 128
    conv3x3_mfma<128, 128, true><<<cgrid, 256, 0, stream>>>(t1, wb_c1w2, c1b2, r2, 128, 0);
    // 5. aux = relu(conv(aux_in, aux_w))       128 -> 64   -> cat[:, 64:128]
    conv3x3_mfma<128, 64, true><<<cgrid, 256, 0, stream>>>(r2, wb_aux, aux_b, cat, 128, 64);
    // 6. x1 = relu(conv(cat, fw1))             128 -> 64
    conv3x3_mfma<128, 64, true><<<cgrid, 256, 0, stream>>>(cat, wb_fw1, fb1, r2, 64, 0);
    // 7. x2 = conv(x1, fw2)                    64 -> 64    -> d_out
    conv3x3_mfma<64, 64, false><<<cgrid, 256, 0, stream>>>(r2, wb_fw2, fb2, out, 64, 0);
    // 8-10. pool, SE, residual
    pool_kernel<<<BB * 64, 256, 0, stream>>>(out, gbuf);
    se_kernel<<<1, 256, 0, stream>>>(gbuf, se_w1, se_b1, se_w2, se_b2, abuf);
    final_kernel<<<(BB * 64 * HWSZ / 4) / 256, 256, 0, stream>>>(out, cat, abuf);
}

// Round 3
// 1307.580 us; speedup vs baseline: 3.1726x; 1.0191x over previous
//
#include <hip/hip_runtime.h>
#include <math.h>

#define HH 192
#define WW 192
#define HWSZ (HH*WW)
#define BB 4

typedef __attribute__((ext_vector_type(8))) short bf16x8;
typedef __attribute__((ext_vector_type(4))) float f32x4;

__device__ __forceinline__ unsigned short f2bf(float f) {
    unsigned int u = __float_as_uint(f);
    u = (u + 0x7FFFu + ((u >> 16) & 1u)) >> 16;
    return (unsigned short)u;
}

// ---------- weight pack: OIHW fp32 -> [tap][cin/32][cout][32] bf16 ----------
__global__ void wprep_kernel(const float* __restrict__ w, unsigned short* __restrict__ wb,
                             int cout, int cin)
{
    int idx = blockIdx.x * 256 + threadIdx.x;
    int n = cout * cin * 9;
    if (idx >= n) return;
    int o = idx / (cin * 9);
    int rem = idx - o * cin * 9;
    int c = rem / 9;
    int t = rem - c * 9;
    int nch = cin >> 5;
    wb[((t * nch + (c >> 5)) * cout + o) * 32 + (c & 31)] = f2bf(w[idx]);
}

// ---------- dcn weight bf16 convert: [o][c*9+t] layout is already OIHW flat ----------
__global__ void wdef_prep_kernel(const float* __restrict__ w, unsigned short* __restrict__ wb)
{
    int i = blockIdx.x * 256 + threadIdx.x;
    if (i < 64 * 576) wb[i] = f2bf(w[i]);
}

// ---------- 3x3 conv, pad=1: bf16 MFMA implicit GEMM ----------
template<int CIN, int COUT, bool RELU>
__global__ __launch_bounds__(256) void conv3x3_mfma(
    const float* __restrict__ in, const unsigned short* __restrict__ wb,
    const float* __restrict__ bias, float* __restrict__ out,
    int coutTot, int ocOff)
{
    constexpr int NCH = CIN / 32;
    constexpr int NOC = COUT / 16;
    __shared__ __align__(16) unsigned short sx[4 * 72 * 32];

    const int tid = threadIdx.x;
    const int b  = blockIdx.z;
    const int y0 = blockIdx.y * 2;
    const int x0 = blockIdx.x * 64;
    const int wv = tid >> 6, lane = tid & 63;
    const int l15 = lane & 15, kg = lane >> 4;
    const int rowl = wv & 1, sbase = (wv >> 1) * 32;

    f32x4 acc[NOC][2];
#pragma unroll
    for (int oc = 0; oc < NOC; ++oc) {
        acc[oc][0] = (f32x4){0.f, 0.f, 0.f, 0.f};
        acc[oc][1] = (f32x4){0.f, 0.f, 0.f, 0.f};
    }

    for (int ch = 0; ch < NCH; ++ch) {
        const int c0 = ch * 32;
#pragma unroll
        for (int it = 0; it < 9; ++it) {
            int i = tid + it * 256;
            int slot = i % 18;
            int rc = i / 18;
            int cin = rc & 31, r = rc >> 5;
            int yin = y0 - 1 + r;
            int gx = x0 - 4 + slot * 4;
            float4 v = {0.f, 0.f, 0.f, 0.f};
            if (yin >= 0 && yin < HH && gx >= 0 && gx <= WW - 4)
                v = *(const float4*)(in + ((size_t)(b * CIN + c0 + cin) * HH + yin) * WW + gx);
#pragma unroll
            for (int j = 0; j < 4; ++j) {
                int px = slot * 4 + j;
                int g = ((cin >> 3) ^ ((px >> 1) & 3));
                int off = (r * 72 + px) * 32 + (g << 3) + (cin & 7);
                float fv = (j == 0) ? v.x : (j == 1) ? v.y : (j == 2) ? v.z : v.w;
                sx[off] = f2bf(fv);
            }
        }
        __syncthreads();
#pragma unroll
        for (int ky = 0; ky < 3; ++ky) {
#pragma unroll
            for (int kx = 0; kx < 3; ++kx) {
                const int r = rowl + ky;
                const int p0 = sbase + l15 + kx + 3;
                const int p1 = p0 + 16;
                bf16x8 b0 = *(const bf16x8*)&sx[(r * 72 + p0) * 32 + ((kg ^ ((p0 >> 1) & 3)) << 3)];
                bf16x8 b1 = *(const bf16x8*)&sx[(r * 72 + p1) * 32 + ((kg ^ ((p1 >> 1) & 3)) << 3)];
                const unsigned short* wp = wb
                    + ((size_t)(((ky * 3 + kx) * NCH + ch) * COUT) + l15) * 32 + kg * 8;
#pragma unroll
                for (int oc = 0; oc < NOC; ++oc) {
                    bf16x8 a = *(const bf16x8*)(wp + oc * 16 * 32);
                    acc[oc][0] = __builtin_amdgcn_mfma_f32_16x16x32_bf16(a, b0, acc[oc][0], 0, 0, 0);
                    acc[oc][1] = __builtin_amdgcn_mfma_f32_16x16x32_bf16(a, b1, acc[oc][1], 0, 0, 0);
                }
            }
        }
        __syncthreads();
    }
    const int y = y0 + rowl;
    float* obase = out + (size_t)(b * coutTot + ocOff) * HWSZ + y * WW + x0;
#pragma unroll
    for (int oc = 0; oc < NOC; ++oc) {
#pragma unroll
        for (int st = 0; st < 2; ++st) {
            int xo = sbase + st * 16 + l15;
#pragma unroll
            for (int j = 0; j < 4; ++j) {
                int cout = oc * 16 + kg * 4 + j;
                float rv = acc[oc][st][j] + bias[cout];
                if (RELU) rv = fmaxf(rv, 0.f);
                obase[(size_t)cout * HWSZ + xo] = rv;
            }
        }
    }
}

// ---------- deformable conv: sample->LDS (bf16) then MFMA implicit GEMM ----------
// block = 64 px (one row strip) x 256 threads. Sampling: thread = (px 0..63, group wv).
// LDS: sampled[64 px][288 K] bf16, row stride 296 shorts (148 dw ≡ 20 mod 32:
// b128 reads 2-way/free, 16B aligned). Two halves (4 groups each) reuse the buffer.
// MFMA: wave wv owns px strip wv*16..+16, computes 16px x 64out, K=288 per half.
__global__ __launch_bounds__(256) void deform_mfma(
    const float* __restrict__ x, const float* __restrict__ off,
    const unsigned short* __restrict__ wdefb, const float* __restrict__ bias,
    float* __restrict__ cat)
{
    __shared__ __align__(16) unsigned short smp[64 * 296];

    const int tid = threadIdx.x;
    const int lane = tid & 63, wv = tid >> 6;
    const int l15 = lane & 15, kg = lane >> 4;
    const int b = blockIdx.z;
    const int y = blockIdx.y;
    const int x0 = blockIdx.x * 64;
    const int px = tid & 63;
    const int gx = x0 + px;

    f32x4 acc[4];
#pragma unroll
    for (int oc = 0; oc < 4; ++oc) acc[oc] = (f32x4){0.f, 0.f, 0.f, 0.f};

    for (int h = 0; h < 2; ++h) {
        const int g = h * 4 + wv;
        const float* xg = x + (size_t)(b * 64 + g * 8) * HWSZ;
#pragma unroll
        for (int k = 0; k < 9; ++k) {
            const int kyy = k / 3, kxx = k % 3;
            size_t oidx = ((size_t)(b * 144 + g * 18 + k * 2) * HH + y) * WW + gx;
            float dy = off[oidx];
            float dx = off[oidx + HWSZ];
            float pyf = (float)(y + kyy - 1) + dy;
            float pxf = (float)(gx + kxx - 1) + dx;
            float fy = floorf(pyf), fx = floorf(pxf);
            float wy = pyf - fy, wx = pxf - fx;
            int iy = (int)fy, ix = (int)fx;
            float w00 = (1.f - wy) * (1.f - wx), w01 = (1.f - wy) * wx;
            float w10 = wy * (1.f - wx),         w11 = wy * wx;
            bool y0v = (iy >= 0) && (iy < HH);
            bool y1v = (iy + 1 >= 0) && (iy + 1 < HH);
            bool x0v = (ix >= 0) && (ix < WW);
            bool x1v = (ix + 1 >= 0) && (ix + 1 < WW);
            if (!(y0v && x0v)) w00 = 0.f;
            if (!(y0v && x1v)) w01 = 0.f;
            if (!(y1v && x0v)) w10 = 0.f;
            if (!(y1v && x1v)) w11 = 0.f;
            int cy0 = min(max(iy, 0), HH - 1),     cy1 = min(max(iy + 1, 0), HH - 1);
            int cx0 = min(max(ix, 0), WW - 1),     cx1 = min(max(ix + 1, 0), WW - 1);
            int i00 = cy0 * WW + cx0, i01 = cy0 * WW + cx1;
            int i10 = cy1 * WW + cx0, i11 = cy1 * WW + cx1;
#pragma unroll
            for (int cc = 0; cc < 8; ++cc) {
                const float* xp = xg + (size_t)cc * HWSZ;
                float v = xp[i00] * w00 + xp[i01] * w01 + xp[i10] * w10 + xp[i11] * w11;
                smp[px * 296 + (wv * 8 + cc) * 9 + k] = f2bf(v);
            }
        }
        __syncthreads();
        // MFMA phase: A = wdefb[o][576] (K = c*9+t), B = smp
        const unsigned short* wrow = wdefb + (size_t)l15 * 576 + h * 288 + kg * 8;
        const unsigned short* brow = smp + (wv * 16 + l15) * 296 + kg * 8;
#pragma unroll
        for (int chunk = 0; chunk < 9; ++chunk) {
            bf16x8 bfrag = *(const bf16x8*)(brow + chunk * 32);
#pragma unroll
            for (int oc = 0; oc < 4; ++oc) {
                bf16x8 afrag = *(const bf16x8*)(wrow + (size_t)oc * 16 * 576 + chunk * 32);
                acc[oc] = __builtin_amdgcn_mfma_f32_16x16x32_bf16(afrag, bfrag, acc[oc], 0, 0, 0);
            }
        }
        __syncthreads();
    }
    const int xo = x0 + wv * 16 + l15;
#pragma unroll
    for (int oc = 0; oc < 4; ++oc) {
#pragma unroll
        for (int j = 0; j < 4; ++j) {
            int o = oc * 16 + kg * 4 + j;
            float r = fmaxf(acc[oc][j] + bias[o], 0.f);
            cat[((size_t)(b * 128 + o) * HH + y) * WW + xo] = r;
        }
    }
}

// ---------------- global average pool ----------------
__global__ __launch_bounds__(256) void pool_kernel(const float* __restrict__ x, float* __restrict__ gout)
{
    int bc = blockIdx.x;
    const float* p = x + (size_t)bc * HWSZ;
    int tid = threadIdx.x;
    float s = 0.f;
    for (int i = tid * 4; i < HWSZ; i += 256 * 4) {
        float4 v = *reinterpret_cast<const float4*>(p + i);
        s += v.x + v.y + v.z + v.w;
    }
#pragma unroll
    for (int o = 32; o > 0; o >>= 1) s += __shfl_down(s, o, 64);
    __shared__ float red[4];
    if ((tid & 63) == 0) red[tid >> 6] = s;
    __syncthreads();
    if (tid == 0) gout[bc] = (red[0] + red[1] + red[2] + red[3]) * (1.f / (float)HWSZ);
}

// ---------------- SE MLP ----------------
__global__ __launch_bounds__(256) void se_kernel(
    const float* __restrict__ g, const float* __restrict__ w1, const float* __restrict__ b1,
    const float* __restrict__ w2, const float* __restrict__ b2, float* __restrict__ a)
{
    __shared__ float sg[BB * 64];
    __shared__ float sh[BB * 32];
    int tid = threadIdx.x;
    sg[tid] = g[tid];
    __syncthreads();
    if (tid < BB * 32) {
        int b = tid / 32, h = tid % 32;
        float s = b1[h];
        for (int c = 0; c < 64; ++c) s += sg[b * 64 + c] * w1[h * 64 + c];
        sh[b * 32 + h] = fmaxf(s, 0.f);
    }
    __syncthreads();
    {
        int b = tid / 64, o = tid % 64;
        float s = b2[o];
        for (int h = 0; h < 32; ++h) s += sh[b * 32 + h] * w2[o * 32 + h];
        a[tid] = 1.f / (1.f + expf(-s));
    }
}

// ---------------- residual + SE scale ----------------
__global__ __launch_bounds__(256) void final_kernel(
    float* __restrict__ out, const float* __restrict__ cat, const float* __restrict__ a)
{
    const int VPC = HWSZ / 4;
    int v = blockIdx.x * 256 + threadIdx.x;
    int bc = v / VPC, within = v % VPC;
    int b = bc >> 6, c = bc & 63;
    float av = a[bc];
    float4 xo = reinterpret_cast<float4*>(out)[v];
    float4 df = reinterpret_cast<const float4*>(cat)[(size_t)(b * 128 + c) * VPC + within];
    float4 r;
    r.x = df.x + xo.x * av;
    r.y = df.y + xo.y * av;
    r.z = df.z + xo.z * av;
    r.w = df.w + xo.w * av;
    reinterpret_cast<float4*>(out)[v] = r;
}

extern "C" void kernel_launch(void* const* d_in, const int* in_sizes, int n_in,
                              void* d_out, int out_size, void* d_ws, size_t ws_size,
                              hipStream_t stream) {
    const float* mv     = (const float*)d_in[0];
    const float* ref    = (const float*)d_in[1];
    const float* head_w = (const float*)d_in[2];
    const float* head_b = (const float*)d_in[3];
    const float* dcn_w  = (const float*)d_in[4];
    const float* dcn_b  = (const float*)d_in[5];
    const float* c1w1   = (const float*)d_in[6];
    const float* c1b1   = (const float*)d_in[7];
    const float* c1w2   = (const float*)d_in[8];
    const float* c1b2   = (const float*)d_in[9];
    const float* aux_w  = (const float*)d_in[10];
    const float* aux_b  = (const float*)d_in[11];
    const float* fw1    = (const float*)d_in[12];
    const float* fb1    = (const float*)d_in[13];
    const float* fw2    = (const float*)d_in[14];
    const float* fb2    = (const float*)d_in[15];
    const float* se_w1  = (const float*)d_in[16];
    const float* se_b1  = (const float*)d_in[17];
    const float* se_w2  = (const float*)d_in[18];
    const float* se_b2  = (const float*)d_in[19];
    float* out = (float*)d_out;

    float* ws = (float*)d_ws;
    const size_t SZ_OFF = (size_t)BB * 144 * HWSZ;
    const size_t SZ_128 = (size_t)BB * 128 * HWSZ;
    float* off_buf = ws;                 // region 1 (reused for t1)
    float* t1      = ws;
    float* r2      = ws + SZ_OFF;        // region 2: aux_in, later x1
    float* cat     = r2 + SZ_128;        // region 3: [def(0:64) | aux(64:128)]
    float* wT      = cat + SZ_128;       // 36864 floats of scratch
    float* gbuf    = wT + 64 * 64 * 9;
    float* abuf    = gbuf + 256;
    unsigned short* wdefb = (unsigned short*)wT;      // 64*576 bf16
    unsigned short* wbb = (unsigned short*)(abuf + 256);
    unsigned short* wb_head = wbb;                    // 144*128*9
    unsigned short* wb_c1w1 = wb_head + 165888;       // 128*64*9
    unsigned short* wb_c1w2 = wb_c1w1 + 73728;        // 128*128*9
    unsigned short* wb_aux  = wb_c1w2 + 147456;       // 64*128*9
    unsigned short* wb_fw1  = wb_aux  + 73728;        // 64*128*9
    unsigned short* wb_fw2  = wb_fw1  + 73728;        // 64*64*9

    // weight prep
    wdef_prep_kernel<<<144, 256, 0, stream>>>(dcn_w, wdefb);
    wprep_kernel<<<(144*128*9 + 255)/256, 256, 0, stream>>>(head_w, wb_head, 144, 128);
    wprep_kernel<<<(128*64*9  + 255)/256, 256, 0, stream>>>(c1w1,   wb_c1w1, 128, 64);
    wprep_kernel<<<(128*128*9 + 255)/256, 256, 0, stream>>>(c1w2,   wb_c1w2, 128, 128);
    wprep_kernel<<<(64*128*9  + 255)/256, 256, 0, stream>>>(aux_w,  wb_aux,  64, 128);
    wprep_kernel<<<(64*128*9  + 255)/256, 256, 0, stream>>>(fw1,    wb_fw1,  64, 128);
    wprep_kernel<<<(64*64*9   + 255)/256, 256, 0, stream>>>(fw2,    wb_fw2,  64, 64);

    dim3 cgrid(3, 96, BB);

    // 1. offsets = conv(mv, head_w)            128 -> 144
    conv3x3_mfma<128, 144, false><<<cgrid, 256, 0, stream>>>(mv, wb_head, head_b, off_buf, 144, 0);
    // 2. def_feat = relu(deform(ref, offsets)) -> cat[:, 0:64]
    deform_mfma<<<dim3(3, 192, BB), 256, 0, stream>>>(ref, off_buf, wdefb, dcn_b, cat);
    // 3. t1 = relu(conv(ref, c1w1))            64 -> 128   (overwrites off region)
    conv3x3_mfma<64, 128, true><<<cgrid, 256, 0, stream>>>(ref, wb_c1w1, c1b1, t1, 128, 0);
    // 4. aux_in = relu(conv(t1, c1w2))         128 -> 128
    conv3x3_mfma<128, 128, true><<<cgrid, 256, 0, stream>>>(t1, wb_c1w2, c1b2, r2, 128, 0);
    // 5. aux = relu(conv(aux_in, aux_w))       128 -> 64   -> cat[:, 64:128]
    conv3x3_mfma<128, 64, true><<<cgrid, 256, 0, stream>>>(r2, wb_aux, aux_b, cat, 128, 64);
    // 6. x1 = relu(conv(cat, fw1))             128 -> 64
    conv3x3_mfma<128, 64, true><<<cgrid, 256, 0, stream>>>(cat, wb_fw1, fb1, r2, 64, 0);
    // 7. x2 = conv(x1, fw2)                    64 -> 64    -> d_out
    conv3x3_mfma<64, 64, false><<<cgrid, 256, 0, stream>>>(r2, wb_fw2, fb2, out, 64, 0);
    // 8-10. pool, SE, residual
    pool_kernel<<<BB * 64, 256, 0, stream>>>(out, gbuf);
    se_kernel<<<1, 256, 0, stream>>>(gbuf, se_w1, se_b1, se_w2, se_b2, abuf);
    final_kernel<<<(BB * 64 * HWSZ / 4) / 256, 256, 0, stream>>>(out, cat, abuf);
}

// Round 4
// 703.735 us; speedup vs baseline: 5.8948x; 1.8581x over previous
//
#include <hip/hip_runtime.h>
#include <math.h>

#define HH 192
#define WW 192
#define HWSZ (HH*WW)
#define BB 4

typedef __attribute__((ext_vector_type(8))) short bf16x8;
typedef __attribute__((ext_vector_type(4))) float f32x4;

__device__ __forceinline__ unsigned short f2bf(float f) {
    unsigned int u = __float_as_uint(f);
    u = (u + 0x7FFFu + ((u >> 16) & 1u)) >> 16;
    return (unsigned short)u;
}
__device__ __forceinline__ float bf2f(unsigned short s) {
    return __uint_as_float(((unsigned int)s) << 16);
}

// ---------- weight pack: OIHW fp32 -> [tap][cin/32][cout][32] bf16 ----------
__global__ void wprep_kernel(const float* __restrict__ w, unsigned short* __restrict__ wb,
                             int cout, int cin)
{
    int idx = blockIdx.x * 256 + threadIdx.x;
    int n = cout * cin * 9;
    if (idx >= n) return;
    int o = idx / (cin * 9);
    int rem = idx - o * cin * 9;
    int c = rem / 9;
    int t = rem - c * 9;
    int nch = cin >> 5;
    wb[((t * nch + (c >> 5)) * cout + o) * 32 + (c & 31)] = f2bf(w[idx]);
}

// ---------- dcn weights: w[o][c][k] -> wdefb[(o*2 + c/32)*288 + k*32 + c%32] ----------
__global__ void wdef_prep_kernel(const float* __restrict__ w, unsigned short* __restrict__ wb)
{
    int i = blockIdx.x * 256 + threadIdx.x;
    if (i >= 64 * 576) return;
    int o = i / 576, rem = i % 576;
    int c = rem / 9, k = rem % 9;
    wb[((size_t)(o * 2 + (c >> 5))) * 288 + k * 32 + (c & 31)] = f2bf(w[i]);
}

// ---------- transpose f32 NCHW -> bf16 [b][C/32][H][W][32] ----------
template<int NCH>
__global__ __launch_bounds__(256) void nchw_to_cl32(
    const float* __restrict__ in, unsigned short* __restrict__ outb)
{
    __shared__ float tile[32][68];
    const int tid = threadIdx.x;
    const int bz = blockIdx.z;
    const int b = bz / NCH, ch = bz % NCH;
    const int y = blockIdx.y;
    const int x0 = blockIdx.x * 64;
#pragma unroll
    for (int it = 0; it < 2; ++it) {
        int u = tid + it * 256;
        int c = u >> 4, q = u & 15;
        float4 v = *(const float4*)(in + (((size_t)(b * NCH + ch) * 32 + c) * HH + y) * WW + x0 + q * 4);
        *(float4*)&tile[c][q * 4] = v;
    }
    __syncthreads();
    const int pxl = tid >> 2, c8 = tid & 3;
    bf16x8 ov;
#pragma unroll
    for (int j = 0; j < 8; ++j) ov[j] = (short)f2bf(tile[c8 * 8 + j][pxl]);
    *(bf16x8*)(outb + (((size_t)bz * HH + y) * WW + x0 + pxl) * 32 + c8 * 8) = ov;
}

// ---------- 3x3 conv, pad=1: bf16 cl32 in, MFMA implicit GEMM, 4 strips/A ----------
// block = 128 thr (2 waves), wave = 1 output row x 64 px. LDS [4r][72px][32c] XOR-swz.
template<int CIN, int COUT, bool RELU, bool EPI_F32>
__global__ __launch_bounds__(128, 2) void conv3x3_v2(
    const unsigned short* __restrict__ in, const unsigned short* __restrict__ wb,
    const float* __restrict__ bias, void* __restrict__ outp,
    int cTot, int ocOff)
{
    constexpr int NCH = CIN / 32;
    constexpr int NOC = COUT / 16;
    __shared__ __align__(16) unsigned short sx[4 * 72 * 32];

    const int tid = threadIdx.x;
    const int b  = blockIdx.z;
    const int y0 = blockIdx.y * 2;
    const int x0 = blockIdx.x * 64;
    const int wv = tid >> 6, lane = tid & 63;
    const int l15 = lane & 15, kg = lane >> 4;

    f32x4 acc[NOC][4];
#pragma unroll
    for (int oc = 0; oc < NOC; ++oc)
#pragma unroll
        for (int s = 0; s < 4; ++s) acc[oc][s] = (f32x4){0.f, 0.f, 0.f, 0.f};

    for (int ch = 0; ch < NCH; ++ch) {
        // stage 4 rows x 72 px x 32c (16B units, coalesced)
#pragma unroll
        for (int it = 0; it < 9; ++it) {
            int u = tid + it * 128;
            int r = u / 288;
            int rem = u - r * 288;
            int px = rem >> 2, c8 = rem & 3;
            int yin = y0 - 1 + r;
            int gx  = x0 - 4 + px;
            bf16x8 v = {0,0,0,0,0,0,0,0};
            if (yin >= 0 && yin < HH && gx >= 0 && gx < WW)
                v = *(const bf16x8*)(in + (((size_t)(b * NCH + ch) * HH + yin) * WW + gx) * 32 + c8 * 8);
            *(bf16x8*)&sx[(r * 72 + px) * 32 + ((c8 ^ ((px >> 1) & 3)) << 3)] = v;
        }
        __syncthreads();
#pragma unroll
        for (int ky = 0; ky < 3; ++ky) {
#pragma unroll
            for (int kx = 0; kx < 3; ++kx) {
                const int r = wv + ky;
                bf16x8 bf[4];
#pragma unroll
                for (int s = 0; s < 4; ++s) {
                    int p = s * 16 + l15 + kx + 3;
                    bf[s] = *(const bf16x8*)&sx[(r * 72 + p) * 32 + ((kg ^ ((p >> 1) & 3)) << 3)];
                }
                const unsigned short* wp = wb
                    + ((size_t)(((ky * 3 + kx) * NCH + ch) * COUT) + l15) * 32 + kg * 8;
#pragma unroll
                for (int oc = 0; oc < NOC; ++oc) {
                    bf16x8 a = *(const bf16x8*)(wp + oc * 16 * 32);
#pragma unroll
                    for (int s = 0; s < 4; ++s)
                        acc[oc][s] = __builtin_amdgcn_mfma_f32_16x16x32_bf16(a, bf[s], acc[oc][s], 0, 0, 0);
                }
            }
        }
        __syncthreads();
    }
    const int y = y0 + wv;
    if (EPI_F32) {
        float* out = (float*)outp;
#pragma unroll
        for (int oc = 0; oc < NOC; ++oc)
#pragma unroll
            for (int s = 0; s < 4; ++s) {
                int xo = x0 + s * 16 + l15;
#pragma unroll
                for (int j = 0; j < 4; ++j) {
                    int cout = ocOff + oc * 16 + kg * 4 + j;
                    float rv = acc[oc][s][j] + bias[cout];
                    if (RELU) rv = fmaxf(rv, 0.f);
                    out[((size_t)(b * cTot + cout) * HH + y) * WW + xo] = rv;
                }
            }
    } else {
        unsigned short* out = (unsigned short*)outp;
#pragma unroll
        for (int oc = 0; oc < NOC; ++oc) {
            int o0 = ocOff + oc * 16 + kg * 4;
#pragma unroll
            for (int s = 0; s < 4; ++s) {
                int xo = x0 + s * 16 + l15;
                ushort4 u;
                float r0 = acc[oc][s][0] + bias[o0 + 0];
                float r1 = acc[oc][s][1] + bias[o0 + 1];
                float r2 = acc[oc][s][2] + bias[o0 + 2];
                float r3 = acc[oc][s][3] + bias[o0 + 3];
                if (RELU) { r0 = fmaxf(r0,0.f); r1 = fmaxf(r1,0.f); r2 = fmaxf(r2,0.f); r3 = fmaxf(r3,0.f); }
                u.x = f2bf(r0); u.y = f2bf(r1); u.z = f2bf(r2); u.w = f2bf(r3);
                *(ushort4*)(out + ((((size_t)(b * cTot + (o0 >> 5)) * HH + y) * WW + xo) * 32) + (o0 & 31)) = u;
            }
        }
    }
}

// ---------- deformable conv: cl32 bf16 source, 16B corner gathers, MFMA ----------
__global__ __launch_bounds__(256, 4) void deform_v2(
    const unsigned short* __restrict__ xb, const float* __restrict__ off,
    const unsigned short* __restrict__ wdefb, const float* __restrict__ bias,
    unsigned short* __restrict__ cat)
{
    __shared__ __align__(16) unsigned short smp[64 * 296];
    const int tid = threadIdx.x;
    const int wv = tid >> 6, lane = tid & 63;
    const int l15 = lane & 15, kg = lane >> 4;
    const int b = blockIdx.z;
    const int y = blockIdx.y;
    const int x0 = blockIdx.x * 64;
    const int px = tid & 63;
    const int gx = x0 + px;

    f32x4 acc[4];
#pragma unroll
    for (int oc = 0; oc < 4; ++oc) acc[oc] = (f32x4){0.f, 0.f, 0.f, 0.f};

    for (int h = 0; h < 2; ++h) {
        const int g = h * 4 + wv;
        const unsigned short* xgb = xb + ((size_t)(b * 2 + (g >> 2)) * HH * WW) * 32 + (g & 3) * 8;
#pragma unroll
        for (int k = 0; k < 9; ++k) {
            const int kyy = k / 3, kxx = k % 3;
            size_t oidx = ((size_t)(b * 144 + g * 18 + k * 2) * HH + y) * WW + gx;
            float dy = off[oidx];
            float dx = off[oidx + HWSZ];
            float pyf = (float)(y + kyy - 1) + dy;
            float pxf = (float)(gx + kxx - 1) + dx;
            float fy = floorf(pyf), fx = floorf(pxf);
            float wy = pyf - fy, wx = pxf - fx;
            int iy = (int)fy, ix = (int)fx;
            float w00 = (1.f - wy) * (1.f - wx), w01 = (1.f - wy) * wx;
            float w10 = wy * (1.f - wx),         w11 = wy * wx;
            bool y0v = (iy >= 0) && (iy < HH);
            bool y1v = (iy + 1 >= 0) && (iy + 1 < HH);
            bool x0v = (ix >= 0) && (ix < WW);
            bool x1v = (ix + 1 >= 0) && (ix + 1 < WW);
            if (!(y0v && x0v)) w00 = 0.f;
            if (!(y0v && x1v)) w01 = 0.f;
            if (!(y1v && x0v)) w10 = 0.f;
            if (!(y1v && x1v)) w11 = 0.f;
            int cy0 = min(max(iy, 0), HH - 1),     cy1 = min(max(iy + 1, 0), HH - 1);
            int cx0 = min(max(ix, 0), WW - 1),     cx1 = min(max(ix + 1, 0), WW - 1);
            bf16x8 v00 = *(const bf16x8*)(xgb + ((size_t)cy0 * WW + cx0) * 32);
            bf16x8 v01 = *(const bf16x8*)(xgb + ((size_t)cy0 * WW + cx1) * 32);
            bf16x8 v10 = *(const bf16x8*)(xgb + ((size_t)cy1 * WW + cx0) * 32);
            bf16x8 v11 = *(const bf16x8*)(xgb + ((size_t)cy1 * WW + cx1) * 32);
            bf16x8 ov;
#pragma unroll
            for (int cc = 0; cc < 8; ++cc) {
                float s = bf2f((unsigned short)v00[cc]) * w00
                        + bf2f((unsigned short)v01[cc]) * w01
                        + bf2f((unsigned short)v10[cc]) * w10
                        + bf2f((unsigned short)v11[cc]) * w11;
                ov[cc] = (short)f2bf(s);
            }
            *(bf16x8*)&smp[px * 296 + k * 32 + wv * 8] = ov;
        }
        __syncthreads();
        const unsigned short* arow = wdefb + ((size_t)(l15 * 2 + h)) * 288 + kg * 8;
        const unsigned short* brow = smp + (wv * 16 + l15) * 296 + kg * 8;
#pragma unroll
        for (int chunk = 0; chunk < 9; ++chunk) {
            bf16x8 bfrag = *(const bf16x8*)(brow + chunk * 32);
#pragma unroll
            for (int oc = 0; oc < 4; ++oc) {
                bf16x8 afrag = *(const bf16x8*)(arow + (size_t)oc * 16 * 2 * 288 + chunk * 32);
                acc[oc] = __builtin_amdgcn_mfma_f32_16x16x32_bf16(afrag, bfrag, acc[oc], 0, 0, 0);
            }
        }
        __syncthreads();
    }
    const int xo = x0 + wv * 16 + l15;
#pragma unroll
    for (int oc = 0; oc < 4; ++oc) {
        int o0 = oc * 16 + kg * 4;
        ushort4 u;
        u.x = f2bf(fmaxf(acc[oc][0] + bias[o0 + 0], 0.f));
        u.y = f2bf(fmaxf(acc[oc][1] + bias[o0 + 1], 0.f));
        u.z = f2bf(fmaxf(acc[oc][2] + bias[o0 + 2], 0.f));
        u.w = f2bf(fmaxf(acc[oc][3] + bias[o0 + 3], 0.f));
        *(ushort4*)(cat + ((((size_t)(b * 4 + (o0 >> 5)) * HH + y) * WW + xo) * 32) + (o0 & 31)) = u;
    }
}

// ---------------- global average pool ----------------
__global__ __launch_bounds__(256) void pool_kernel(const float* __restrict__ x, float* __restrict__ gout)
{
    int bc = blockIdx.x;
    const float* p = x + (size_t)bc * HWSZ;
    int tid = threadIdx.x;
    float s = 0.f;
    for (int i = tid * 4; i < HWSZ; i += 256 * 4) {
        float4 v = *reinterpret_cast<const float4*>(p + i);
        s += v.x + v.y + v.z + v.w;
    }
#pragma unroll
    for (int o = 32; o > 0; o >>= 1) s += __shfl_down(s, o, 64);
    __shared__ float red[4];
    if ((tid & 63) == 0) red[tid >> 6] = s;
    __syncthreads();
    if (tid == 0) gout[bc] = (red[0] + red[1] + red[2] + red[3]) * (1.f / (float)HWSZ);
}

// ---------------- SE MLP ----------------
__global__ __launch_bounds__(256) void se_kernel(
    const float* __restrict__ g, const float* __restrict__ w1, const float* __restrict__ b1,
    const float* __restrict__ w2, const float* __restrict__ b2, float* __restrict__ a)
{
    __shared__ float sg[BB * 64];
    __shared__ float sh[BB * 32];
    int tid = threadIdx.x;
    sg[tid] = g[tid];
    __syncthreads();
    if (tid < BB * 32) {
        int b = tid / 32, h = tid % 32;
        float s = b1[h];
        for (int c = 0; c < 64; ++c) s += sg[b * 64 + c] * w1[h * 64 + c];
        sh[b * 32 + h] = fmaxf(s, 0.f);
    }
    __syncthreads();
    {
        int b = tid / 64, o = tid % 64;
        float s = b2[o];
        for (int h = 0; h < 32; ++h) s += sh[b * 32 + h] * w2[o * 32 + h];
        a[tid] = 1.f / (1.f + expf(-s));
    }
}

// ---------------- residual (bf16 cl32 def) + SE scale ----------------
__global__ __launch_bounds__(256) void final_v2(
    float* __restrict__ out, const unsigned short* __restrict__ catb, const float* __restrict__ a)
{
    const int VPC = HWSZ / 4;
    int v = blockIdx.x * 256 + threadIdx.x;
    int bc = v / VPC, within = v - bc * VPC;
    int b = bc >> 6, c = bc & 63;
    float av = a[bc];
    int pix = within * 4;
    int y = pix / WW, x = pix - y * WW;
    const unsigned short* dbase = catb
        + (((size_t)(b * 4 + (c >> 5)) * HH + y) * WW + x) * 32 + (c & 31);
    float4 xo = reinterpret_cast<float4*>(out)[v];
    float4 r;
    r.x = bf2f(dbase[0])  + xo.x * av;
    r.y = bf2f(dbase[32]) + xo.y * av;
    r.z = bf2f(dbase[64]) + xo.z * av;
    r.w = bf2f(dbase[96]) + xo.w * av;
    reinterpret_cast<float4*>(out)[v] = r;
}

extern "C" void kernel_launch(void* const* d_in, const int* in_sizes, int n_in,
                              void* d_out, int out_size, void* d_ws, size_t ws_size,
                              hipStream_t stream) {
    const float* mv     = (const float*)d_in[0];
    const float* ref    = (const float*)d_in[1];
    const float* head_w = (const float*)d_in[2];
    const float* head_b = (const float*)d_in[3];
    const float* dcn_w  = (const float*)d_in[4];
    const float* dcn_b  = (const float*)d_in[5];
    const float* c1w1   = (const float*)d_in[6];
    const float* c1b1   = (const float*)d_in[7];
    const float* c1w2   = (const float*)d_in[8];
    const float* c1b2   = (const float*)d_in[9];
    const float* aux_w  = (const float*)d_in[10];
    const float* aux_b  = (const float*)d_in[11];
    const float* fw1    = (const float*)d_in[12];
    const float* fb1    = (const float*)d_in[13];
    const float* fw2    = (const float*)d_in[14];
    const float* fb2    = (const float*)d_in[15];
    const float* se_w1  = (const float*)d_in[16];
    const float* se_b1  = (const float*)d_in[17];
    const float* se_w2  = (const float*)d_in[18];
    const float* se_b2  = (const float*)d_in[19];
    float* out = (float*)d_out;

    float* ws = (float*)d_ws;
    float* off_buf           = ws;                                   // 21,233,664 f (f32 offsets)
    unsigned short* mvb      = (unsigned short*)(ws + 21233664);     // 18,874,368 sh
    unsigned short* refb     = (unsigned short*)(ws + 30670848);     //  9,437,184 sh
    unsigned short* catb     = (unsigned short*)(ws + 35389440);     // 18,874,368 sh
    unsigned short* r2b      = (unsigned short*)(ws + 44826624);     // 18,874,368 sh
    unsigned short* wdefb    = (unsigned short*)(ws + 54263808);     //     36,864 sh
    unsigned short* wbb      = (unsigned short*)(ws + 54282240);     //    571,392 sh
    float* gbuf              = ws + 54567936;
    float* abuf              = gbuf + 256;
    unsigned short* t1b      = (unsigned short*)off_buf;             // reuses off region after deform

    unsigned short* wb_head = wbb;                    // 144*128*9
    unsigned short* wb_c1w1 = wb_head + 165888;       // 128*64*9
    unsigned short* wb_c1w2 = wb_c1w1 + 73728;        // 128*128*9
    unsigned short* wb_aux  = wb_c1w2 + 147456;       // 64*128*9
    unsigned short* wb_fw1  = wb_aux  + 73728;        // 64*128*9
    unsigned short* wb_fw2  = wb_fw1  + 73728;        // 64*64*9

    // weight prep
    wdef_prep_kernel<<<144, 256, 0, stream>>>(dcn_w, wdefb);
    wprep_kernel<<<(144*128*9 + 255)/256, 256, 0, stream>>>(head_w, wb_head, 144, 128);
    wprep_kernel<<<(128*64*9  + 255)/256, 256, 0, stream>>>(c1w1,   wb_c1w1, 128, 64);
    wprep_kernel<<<(128*128*9 + 255)/256, 256, 0, stream>>>(c1w2,   wb_c1w2, 128, 128);
    wprep_kernel<<<(64*128*9  + 255)/256, 256, 0, stream>>>(aux_w,  wb_aux,  64, 128);
    wprep_kernel<<<(64*128*9  + 255)/256, 256, 0, stream>>>(fw1,    wb_fw1,  64, 128);
    wprep_kernel<<<(64*64*9   + 255)/256, 256, 0, stream>>>(fw2,    wb_fw2,  64, 64);

    // activation transposes to bf16 cl32
    nchw_to_cl32<4><<<dim3(3, 192, BB * 4), 256, 0, stream>>>(mv,  mvb);
    nchw_to_cl32<2><<<dim3(3, 192, BB * 2), 256, 0, stream>>>(ref, refb);

    dim3 cgrid(3, 96, BB);

    // 1. offsets = conv(mv)                    128 -> 144   (f32 NCHW out)
    conv3x3_v2<128, 144, false, true><<<cgrid, 128, 0, stream>>>(mvb, wb_head, head_b, off_buf, 144, 0);
    // 2. def_feat = relu(deform(ref, offsets)) -> catb chunks 0-1
    deform_v2<<<dim3(3, 192, BB), 256, 0, stream>>>(refb, off_buf, wdefb, dcn_b, catb);
    // 3. t1 = relu(conv(ref, c1w1))            64 -> 128    (bf16 cl32, reuses off region)
    conv3x3_v2<64, 128, true, false><<<cgrid, 128, 0, stream>>>(refb, wb_c1w1, c1b1, t1b, 4, 0);
    // 4. aux_in = relu(conv(t1, c1w2))         128 -> 128
    conv3x3_v2<128, 128, true, false><<<cgrid, 128, 0, stream>>>(t1b, wb_c1w2, c1b2, r2b, 4, 0);
    // 5. aux = relu(conv(aux_in, aux_w))       128 -> 64    -> catb chunks 2-3
    conv3x3_v2<128, 64, true, false><<<cgrid, 128, 0, stream>>>(r2b, wb_aux, aux_b, catb, 4, 64);
    // 6. x1 = relu(conv(cat, fw1))             128 -> 64
    conv3x3_v2<128, 64, true, false><<<cgrid, 128, 0, stream>>>(catb, wb_fw1, fb1, r2b, 2, 0);
    // 7. x2 = conv(x1, fw2)                    64 -> 64     -> d_out (f32 NCHW)
    conv3x3_v2<64, 64, false, true><<<cgrid, 128, 0, stream>>>(r2b, wb_fw2, fb2, out, 64, 0);
    // 8-10. pool, SE, residual
    pool_kernel<<<BB * 64, 256, 0, stream>>>(out, gbuf);
    se_kernel<<<1, 256, 0, stream>>>(gbuf, se_w1, se_b1, se_w2, se_b2, abuf);
    final_v2<<<9216, 256, 0, stream>>>(out, catb, abuf);
}